// Round 7
// baseline (221.079 us; speedup 1.0000x reference)
//
#include <hip/hip_runtime.h>
#include <stdint.h>

#define S_ 2048

typedef __bf16 bf16x8 __attribute__((ext_vector_type(8)));
typedef float f32x4 __attribute__((ext_vector_type(4)));
typedef unsigned int u32x4 __attribute__((ext_vector_type(4)));

union FragU { u32x4 u; bf16x8 v; unsigned short s[8]; };

__device__ __forceinline__ unsigned short f2bf(float f) {
    unsigned int u = __builtin_bit_cast(unsigned int, f);
    u += 0x7fffu + ((u >> 16) & 1u);   // round-to-nearest-even
    return (unsigned short)(u >> 16);
}
__device__ __forceinline__ unsigned int pk2(float a, float b) {
    return (unsigned int)f2bf(a) | ((unsigned int)f2bf(b) << 16);
}
__device__ __forceinline__ void gl_lds16(const void* g, void* l) {
    __builtin_amdgcn_global_load_lds(
        (const __attribute__((address_space(1))) unsigned int*)g,
        (__attribute__((address_space(3))) unsigned int*)l, 16, 0, 0);
}

// ---------- Stage 0a: W fp32 -> bf16 in MFMA B-frag layout ----------
// Wt frag f = mat*128 + cg*32 + s : 64 lanes x 16B. Lane(lm,quad) holds
// W[mat][col=cg*16+lm][k = s*32 + quad*8 .. +8].
__global__ __launch_bounds__(256) void cvt_w_kernel(
    const float* __restrict__ wq, const float* __restrict__ wk,
    const float* __restrict__ wv, u32x4* __restrict__ Wt4)
{
    const int lane = threadIdx.x & 63;
    const int lm = lane & 15, quad = lane >> 4;
    const int f = blockIdx.x * 4 + (threadIdx.x >> 6);   // 0..383
    const int mat = f >> 7, cg = (f >> 5) & 3, s = f & 31;
    const float* W = (mat == 0) ? wq : (mat == 1) ? wk : wv;
    const float* src = W + (cg * 16 + lm) * 1024 + s * 32 + quad * 8;
    float4 a = *(const float4*)(src);
    float4 b = *(const float4*)(src + 4);
    FragU o;
    o.u[0] = pk2(a.x, a.y); o.u[1] = pk2(a.z, a.w);
    o.u[2] = pk2(b.x, b.y); o.u[3] = pk2(b.z, b.w);
    Wt4[f * 64 + lane] = o.u;
}

// ---------- Stage 0b: mask int32 -> bitmask (64 MB -> 2 MB), deep queue ----------
__global__ __launch_bounds__(256) void mask_pack(
    const int* __restrict__ mask, unsigned long long* __restrict__ bits)
{
    const int lane = threadIdx.x & 63;
    const int wid = (blockIdx.x * 256 + threadIdx.x) >> 6;  // 0..32767
    const int* p = mask + wid * 512 + lane;
    int m[8];
    #pragma unroll
    for (int j = 0; j < 8; ++j) m[j] = p[j * 64];           // 8 loads in flight
    #pragma unroll
    for (int j = 0; j < 8; ++j) {
        unsigned long long b = __ballot(m[j] != 0);         // bit L = key j*64+L
        if (lane == 0) bits[wid * 8 + j] = b;
    }
}

// ---------- Stage 1: projection GEMM, K-quartered pipelined staging ----------
// grid (512, 3), block 256 = 4 waves; block = 16 rows x 64 cols, full K=1024.
// K split into 4 quarters (16 rows x 256 fp32 = 16 KB). Double-buffered:
// stage(q+1) is issued BEFORE compute(q), so the next burst is in flight
// across every barrier -> continuous HBM demand. LDS 2x16.6 KB -> 4 blocks/CU.
__global__ __launch_bounds__(256, 4) void proj_kernel(
    const float* __restrict__ Q, const float* __restrict__ K, const float* __restrict__ V,
    const u32x4* __restrict__ Wt4,
    const float* __restrict__ Bq, const float* __restrict__ Bk, const float* __restrict__ Bv,
    unsigned short* __restrict__ Qb, unsigned short* __restrict__ Kb,
    unsigned short* __restrict__ Vf)            // Vf: B-frag layout, see epilogue
{
    const int tid = threadIdx.x;
    const int w = tid >> 6, lane = tid & 63;
    const int lm = lane & 15, quad = lane >> 4;
    const int mat = blockIdx.y;
    const int row0 = blockIdx.x * 16;

    __shared__ __align__(16) float Xq[2][16][260];   // pad 256->260 dw: 2-way only

    const float* X    = (mat == 0) ? Q  : (mat == 1) ? K  : V;
    const float* Bias = (mat == 0) ? Bq : (mat == 1) ? Bk : Bv;

    // wave w stages rows [w*4, w*4+4); one 1KB inst per row-quarter
    const float* xg = X + (row0 + w * 4) * 1024 + lane * 4;

    // ---- prologue: stage quarter 0 ----
    #pragma unroll
    for (int r = 0; r < 4; ++r)
        gl_lds16(xg + r * 1024, &Xq[0][w * 4 + r][0]);

    f32x4 acc = {0.f, 0.f, 0.f, 0.f};
    const u32x4* wfrag = Wt4 + (mat * 128 + w * 32) * 64 + lane;

    __syncthreads();                                 // drains stage(0)

    #pragma unroll
    for (int q = 0; q < 4; ++q) {
        // issue next stage first: it flies during compute(q)
        if (q < 3) {
            #pragma unroll
            for (int r = 0; r < 4; ++r)
                gl_lds16(xg + r * 1024 + (q + 1) * 256, &Xq[(q + 1) & 1][w * 4 + r][0]);
        }
        // compute quarter q: 8 K-steps of 32
        #pragma unroll
        for (int s = 0; s < 8; ++s) {
            f32x4 a0 = *(const f32x4*)&Xq[q & 1][lm][s * 32 + quad * 8];
            f32x4 a1 = *(const f32x4*)&Xq[q & 1][lm][s * 32 + quad * 8 + 4];
            FragU af, bfr;
            af.u[0] = pk2(a0[0], a0[1]); af.u[1] = pk2(a0[2], a0[3]);
            af.u[2] = pk2(a1[0], a1[1]); af.u[3] = pk2(a1[2], a1[3]);
            bfr.u = wfrag[(q * 8 + s) * 64];
            acc = __builtin_amdgcn_mfma_f32_16x16x32_bf16(af.v, bfr.v, acc, 0, 0, 0);
        }
        __syncthreads();    // waits stage(q+1) complete; WAR-safe for q+2
    }

    // ---- epilogue: lane holds C[row=quad*4+r][col=w*16+lm] ----
    const int col = w * 16 + lm;
    const float bias = Bias[col];
    if (mat == 2) {
        // Vf: [b][sb=seq/32][dg=dim/16][fraglane][8 bf16]; fraglane=fq*16+lm
        // holds V_[seq=sb*32+fq*8+j][dim=dg*16+lm]
        const int seq0 = row0 + quad * 4;           // global row of r=0
        const int b_ = seq0 >> 11;
        const int s = seq0 & 2047;
        const int sb = s >> 5, s32 = s & 31;
        const int fq = s32 >> 3, j0 = s32 & 7;      // j0 in {0,4}
        ushort4 vv;
        unsigned short* vs = (unsigned short*)&vv;
        #pragma unroll
        for (int r = 0; r < 4; ++r) vs[r] = f2bf(acc[r] + bias);
        char* dst = (char*)Vf + ((b_ * 64 + sb) * 4 + w) * 1024
                    + (fq * 16 + lm) * 16 + j0 * 2;
        *(ushort4*)dst = vv;
    } else {
        unsigned short* dst = (mat == 0) ? Qb : Kb;
        #pragma unroll
        for (int r = 0; r < 4; ++r)
            dst[(row0 + quad * 4 + r) * 64 + col] = f2bf(acc[r] + bias);
    }
}

// ---------- Stage 2: masked attention, bitmask + frag-layout V ----------
// grid (128, 4), block 512 = 8 waves; block = one 16-query tile, all 2048 keys.
// Wave w: keys [w*256,(w+1)*256). p = bit ? exp(s/8) : 0 (exact vs reference
// softmax; scores bounded). No cross-lane ops in the K-loop.
__global__ __launch_bounds__(512) void attn_kernel(
    const unsigned short* __restrict__ Qb, const unsigned short* __restrict__ Kb,
    const u32x4* __restrict__ Vf4, const unsigned long long* __restrict__ bits,
    float* __restrict__ out)
{
    const int tid = threadIdx.x;
    const int w = tid >> 6, lane = tid & 63;
    const int lm = lane & 15, quad = lane >> 4;
    const int q0 = blockIdx.x * 16;
    const int b = blockIdx.y;

    __shared__ unsigned long long Mb[16][32];     // 16 rows x 2048 key-bits
    __shared__ unsigned short Plds[8][16 * 72];
    __shared__ float Olds[8][1024];
    __shared__ float llds[8][16];

    // ---- load bitmask tile (4 KB): one u64 per thread ----
    {
        const int p = tid >> 5, kw = tid & 31;
        Mb[p][kw] = bits[(b * 2048 + q0 + p) * 32 + kw];
    }

    // Q fragments (A-layout)
    FragU qf0, qf1;
    const unsigned short* qptr = Qb + (b * 2048 + q0 + lm) * 64 + quad * 8;
    qf0.u = *(const u32x4*)qptr;
    qf1.u = *(const u32x4*)(qptr + 32);

    f32x4 o[4];
    #pragma unroll
    for (int dt = 0; dt < 4; ++dt) { f32x4 z = {0.f,0.f,0.f,0.f}; o[dt] = z; }
    float lsum[4] = {0.f, 0.f, 0.f, 0.f};

    const unsigned short* kbase = Kb + b * 2048 * 64;
    const u32x4* vbase = Vf4 + (b * 64) * 4 * 64;

    __syncthreads();    // Mb ready

    #pragma unroll
    for (int iter = 0; iter < 4; ++iter) {
        const int k0 = w * 256 + iter * 64;
        const int kw = k0 >> 6;

        // ---- scores: 16q x 64k ----
        f32x4 sc[4];
        #pragma unroll
        for (int ct = 0; ct < 4; ++ct) {
            const unsigned short* kptr = kbase + (k0 + ct * 16 + lm) * 64 + quad * 8;
            FragU kf0, kf1;
            kf0.u = *(const u32x4*)kptr;
            kf1.u = *(const u32x4*)(kptr + 32);
            f32x4 a = {0.f,0.f,0.f,0.f};
            a = __builtin_amdgcn_mfma_f32_16x16x32_bf16(qf0.v, kf0.v, a, 0, 0, 0);
            a = __builtin_amdgcn_mfma_f32_16x16x32_bf16(qf1.v, kf1.v, a, 0, 0, 0);
            sc[ct] = a;
        }

        unsigned long long mb[4];
        #pragma unroll
        for (int r = 0; r < 4; ++r) mb[r] = Mb[quad * 4 + r][kw];

        #pragma unroll
        for (int ct = 0; ct < 4; ++ct) {
            #pragma unroll
            for (int r = 0; r < 4; ++r) {
                float p = ((mb[r] >> (ct * 16 + lm)) & 1ull)
                          ? __expf(sc[ct][r] * 0.125f) : 0.f;
                sc[ct][r] = p;
                lsum[r] += p;
            }
        }

        // ---- P: C-layout -> A-layout via own LDS slice (no barrier) ----
        #pragma unroll
        for (int ct = 0; ct < 4; ++ct)
            #pragma unroll
            for (int r = 0; r < 4; ++r)
                Plds[w][(quad * 4 + r) * 72 + ct * 16 + lm] = f2bf(sc[ct][r]);

        // ---- PV: vf loads lane-contiguous (frag layout) ----
        #pragma unroll
        for (int ks = 0; ks < 2; ++ks) {
            FragU pf;
            pf.u = *(const u32x4*)&Plds[w][lm * 72 + ks * 32 + quad * 8];
            const int sb = (k0 >> 5) + ks;
            #pragma unroll
            for (int dt = 0; dt < 4; ++dt) {
                FragU vf;
                vf.u = vbase[(sb * 4 + dt) * 64 + lane];
                o[dt] = __builtin_amdgcn_mfma_f32_16x16x32_bf16(pf.v, vf.v, o[dt], 0, 0, 0);
            }
        }
    }

    // ---- l reduce over 16-lane row groups ----
    #pragma unroll
    for (int r = 0; r < 4; ++r)
        #pragma unroll
        for (int off = 1; off <= 8; off <<= 1)
            lsum[r] += __shfl_xor(lsum[r], off, 64);

    #pragma unroll
    for (int dt = 0; dt < 4; ++dt)
        #pragma unroll
        for (int r = 0; r < 4; ++r)
            Olds[w][(quad * 4 + r) * 64 + dt * 16 + lm] = o[dt][r];
    if (lm == 0)
        #pragma unroll
        for (int r = 0; r < 4; ++r) llds[w][quad * 4 + r] = lsum[r];
    __syncthreads();

    // ---- merge 8 wave-partials, normalize, store ----
    #pragma unroll
    for (int i = 0; i < 2; ++i) {
        int e = i * 512 + tid;
        int q = e >> 6, d = e & 63;
        float L = 0.f, val = 0.f;
        #pragma unroll
        for (int ww = 0; ww < 8; ++ww) {
            L   += llds[ww][q];
            val += Olds[ww][q * 64 + d];
        }
        out[(b * 2048 + q0 + q) * 64 + d] = val / L;
    }
}

extern "C" void kernel_launch(void* const* d_in, const int* in_sizes, int n_in,
                              void* d_out, int out_size, void* d_ws, size_t ws_size,
                              hipStream_t stream) {
    const float* Q   = (const float*)d_in[0];
    const float* K   = (const float*)d_in[1];
    const float* V   = (const float*)d_in[2];
    const int* mask  = (const int*)d_in[3];
    const float* Wq  = (const float*)d_in[4];
    const float* bq  = (const float*)d_in[5];
    const float* Wk  = (const float*)d_in[6];
    const float* bk  = (const float*)d_in[7];
    const float* Wv  = (const float*)d_in[8];
    const float* bv  = (const float*)d_in[9];
    float* out = (float*)d_out;

    char* ws = (char*)d_ws;
    unsigned short* Qb = (unsigned short*)(ws);                          // 1 MB
    unsigned short* Kb = (unsigned short*)(ws + (1u << 20));             // 1 MB
    unsigned short* Vf = (unsigned short*)(ws + (2u << 20));             // 1 MB
    u32x4* Wt4 = (u32x4*)(ws + (3u << 20));                              // 384 KB
    unsigned long long* bits = (unsigned long long*)(ws + (4u << 20));   // 2 MB

    hipLaunchKernelGGL(cvt_w_kernel, dim3(96), dim3(256), 0, stream, Wq, Wk, Wv, Wt4);
    hipLaunchKernelGGL(mask_pack, dim3(8192), dim3(256), 0, stream, mask, bits);
    hipLaunchKernelGGL(proj_kernel, dim3(512, 3), dim3(256), 0, stream,
                       Q, K, V, Wt4, bq, bk, bv, Qb, Kb, Vf);
    hipLaunchKernelGGL(attn_kernel, dim3(128, 4), dim3(512), 0, stream,
                       Qb, Kb, (const u32x4*)Vf, bits, out);
}

// Round 8
// 215.082 us; speedup vs baseline: 1.0279x; 1.0279x over previous
//
#include <hip/hip_runtime.h>
#include <stdint.h>

#define S_ 2048

typedef __bf16 bf16x8 __attribute__((ext_vector_type(8)));
typedef float f32x4 __attribute__((ext_vector_type(4)));
typedef unsigned int u32x4 __attribute__((ext_vector_type(4)));

union FragU { u32x4 u; bf16x8 v; unsigned short s[8]; };

__device__ __forceinline__ unsigned short f2bf(float f) {
    unsigned int u = __builtin_bit_cast(unsigned int, f);
    u += 0x7fffu + ((u >> 16) & 1u);   // round-to-nearest-even
    return (unsigned short)(u >> 16);
}
__device__ __forceinline__ unsigned int pk2(float a, float b) {
    return (unsigned int)f2bf(a) | ((unsigned int)f2bf(b) << 16);
}
__device__ __forceinline__ void gl_lds16(const void* g, void* l) {
    __builtin_amdgcn_global_load_lds(
        (const __attribute__((address_space(1))) unsigned int*)g,
        (__attribute__((address_space(3))) unsigned int*)l, 16, 0, 0);
}

// ---------- Stage 0a: W fp32 -> bf16 in MFMA B-frag layout ----------
// Wt frag f = mat*128 + cg*32 + s : 64 lanes x 16B. Lane(lm,quad) holds
// W[mat][col=cg*16+lm][k = s*32 + quad*8 .. +8].
__global__ __launch_bounds__(256) void cvt_w_kernel(
    const float* __restrict__ wq, const float* __restrict__ wk,
    const float* __restrict__ wv, u32x4* __restrict__ Wt4)
{
    const int lane = threadIdx.x & 63;
    const int lm = lane & 15, quad = lane >> 4;
    const int f = blockIdx.x * 4 + (threadIdx.x >> 6);   // 0..383
    const int mat = f >> 7, cg = (f >> 5) & 3, s = f & 31;
    const float* W = (mat == 0) ? wq : (mat == 1) ? wk : wv;
    const float* src = W + (cg * 16 + lm) * 1024 + s * 32 + quad * 8;
    float4 a = *(const float4*)(src);
    float4 b = *(const float4*)(src + 4);
    FragU o;
    o.u[0] = pk2(a.x, a.y); o.u[1] = pk2(a.z, a.w);
    o.u[2] = pk2(b.x, b.y); o.u[3] = pk2(b.z, b.w);
    Wt4[f * 64 + lane] = o.u;
}

// ---------- Stage 1: FUSED projection GEMM + mask bit-pack ----------
// grid 3584 x 256 thr. Group g = bid/7, j = bid%7:
//   j<3  : proj block (mat=j, rows [g*16,g*16+16), all 64 cols) — R6 structure:
//          X staged once via 16 gl_lds(16B)/wave, ONE barrier, B-frags from Wt.
//   j>=3 : mask-pack block (wave packs 2048 ints -> 32 u64; 32 loads in flight).
// Interleaving keeps BOTH read streams (QKV 96MB + mask 64MB) in flight
// concurrently — tests the per-kernel read-ceiling theory.
__global__ __launch_bounds__(256, 2) void proj_mask_kernel(
    const float* __restrict__ Q, const float* __restrict__ K, const float* __restrict__ V,
    const u32x4* __restrict__ Wt4,
    const float* __restrict__ Bq, const float* __restrict__ Bk, const float* __restrict__ Bv,
    const int* __restrict__ mask,
    unsigned short* __restrict__ Qb, unsigned short* __restrict__ Kb,
    unsigned short* __restrict__ Vf,            // Vf: B-frag layout, see epilogue
    unsigned long long* __restrict__ bits)
{
    const int tid = threadIdx.x;
    const int w = tid >> 6, lane = tid & 63;
    const int g = blockIdx.x / 7, j = blockIdx.x % 7;

    __shared__ __align__(16) float Xs[16][1028];   // 65.8 KB (2 blocks/CU)

    if (j >= 3) {
        // ---- mask pack: wave wid covers ints [wid*2048, +2048) ----
        const int wid = (g * 4 + (j - 3)) * 4 + w;   // 0..8191
        const int* p = mask + wid * 2048 + lane;
        int mm[32];
        #pragma unroll
        for (int t = 0; t < 32; ++t) mm[t] = p[t * 64];      // 32 loads in flight
        #pragma unroll
        for (int t = 0; t < 32; ++t) {
            unsigned long long bb = __ballot(mm[t] != 0);    // bit L = key t*64+L
            if (lane == 0) bits[wid * 32 + t] = bb;
        }
        return;
    }

    // ---- proj block (R6 structure) ----
    const int lm = lane & 15, quad = lane >> 4;
    const int mat = j;
    const int row0 = g * 16;

    const float* X    = (mat == 0) ? Q  : (mat == 1) ? K  : V;
    const float* Bias = (mat == 0) ? Bq : (mat == 1) ? Bk : Bv;

    // stage: wave w stages rows [w*4, w*4+4), 4 x 1KB insts per row
    #pragma unroll
    for (int i = 0; i < 16; ++i) {
        const int r = w * 4 + (i >> 2);
        const int qd = i & 3;
        gl_lds16(X + (row0 + r) * 1024 + qd * 256 + lane * 4, &Xs[r][qd * 256]);
    }
    __syncthreads();                            // drains vmcnt, data visible

    // K loop: 32 steps of K=32
    f32x4 acc = {0.f, 0.f, 0.f, 0.f};
    const u32x4* wfrag = Wt4 + (mat * 128 + w * 32) * 64 + lane;
    #pragma unroll 8
    for (int s = 0; s < 32; ++s) {
        f32x4 a0 = *(const f32x4*)&Xs[lm][s * 32 + quad * 8];
        f32x4 a1 = *(const f32x4*)&Xs[lm][s * 32 + quad * 8 + 4];
        FragU af, bfr;
        af.u[0] = pk2(a0[0], a0[1]); af.u[1] = pk2(a0[2], a0[3]);
        af.u[2] = pk2(a1[0], a1[1]); af.u[3] = pk2(a1[2], a1[3]);
        bfr.u = wfrag[s * 64];
        acc = __builtin_amdgcn_mfma_f32_16x16x32_bf16(af.v, bfr.v, acc, 0, 0, 0);
    }

    // epilogue: lane holds C[row=quad*4+r][col=w*16+lm]
    const int col = w * 16 + lm;
    const float bias = Bias[col];
    if (mat == 2) {
        // Vf: [b][sb=seq/32][dg=dim/16][fraglane][8 bf16]; fraglane=fq*16+lm
        // holds V_[seq=sb*32+fq*8+jj][dim=dg*16+lm]
        const int seq0 = row0 + quad * 4;
        const int b_ = seq0 >> 11;
        const int s = seq0 & 2047;
        const int sb = s >> 5, s32 = s & 31;
        const int fq = s32 >> 3, j0 = s32 & 7;      // j0 in {0,4}
        ushort4 vv;
        unsigned short* vs = (unsigned short*)&vv;
        #pragma unroll
        for (int r = 0; r < 4; ++r) vs[r] = f2bf(acc[r] + bias);
        char* dst = (char*)Vf + ((b_ * 64 + sb) * 4 + w) * 1024
                    + (fq * 16 + lm) * 16 + j0 * 2;
        *(ushort4*)dst = vv;
    } else {
        unsigned short* dst = (mat == 0) ? Qb : Kb;
        #pragma unroll
        for (int r = 0; r < 4; ++r)
            dst[(row0 + quad * 4 + r) * 64 + col] = f2bf(acc[r] + bias);
    }
}

// ---------- Stage 2: masked attention, bitmask + frag-layout V ----------
// grid (128, 4), block 512 = 8 waves; block = one 16-query tile, all 2048 keys.
// Wave w: keys [w*256,(w+1)*256). p = bit ? exp(s/8) : 0 (exact vs reference
// softmax; scores bounded). No cross-lane ops in the K-loop.
__global__ __launch_bounds__(512) void attn_kernel(
    const unsigned short* __restrict__ Qb, const unsigned short* __restrict__ Kb,
    const u32x4* __restrict__ Vf4, const unsigned long long* __restrict__ bits,
    float* __restrict__ out)
{
    const int tid = threadIdx.x;
    const int w = tid >> 6, lane = tid & 63;
    const int lm = lane & 15, quad = lane >> 4;
    const int q0 = blockIdx.x * 16;
    const int b = blockIdx.y;

    __shared__ unsigned long long Mb[16][32];     // 16 rows x 2048 key-bits
    __shared__ unsigned short Plds[8][16 * 72];
    __shared__ float Olds[8][1024];
    __shared__ float llds[8][16];

    // ---- load bitmask tile (4 KB): one u64 per thread ----
    {
        const int p = tid >> 5, kw = tid & 31;
        Mb[p][kw] = bits[(b * 2048 + q0 + p) * 32 + kw];
    }

    // Q fragments (A-layout)
    FragU qf0, qf1;
    const unsigned short* qptr = Qb + (b * 2048 + q0 + lm) * 64 + quad * 8;
    qf0.u = *(const u32x4*)qptr;
    qf1.u = *(const u32x4*)(qptr + 32);

    f32x4 o[4];
    #pragma unroll
    for (int dt = 0; dt < 4; ++dt) { f32x4 z = {0.f,0.f,0.f,0.f}; o[dt] = z; }
    float lsum[4] = {0.f, 0.f, 0.f, 0.f};

    const unsigned short* kbase = Kb + b * 2048 * 64;
    const u32x4* vbase = Vf4 + (b * 64) * 4 * 64;

    __syncthreads();    // Mb ready

    #pragma unroll
    for (int iter = 0; iter < 4; ++iter) {
        const int k0 = w * 256 + iter * 64;
        const int kw = k0 >> 6;

        // ---- scores: 16q x 64k ----
        f32x4 sc[4];
        #pragma unroll
        for (int ct = 0; ct < 4; ++ct) {
            const unsigned short* kptr = kbase + (k0 + ct * 16 + lm) * 64 + quad * 8;
            FragU kf0, kf1;
            kf0.u = *(const u32x4*)kptr;
            kf1.u = *(const u32x4*)(kptr + 32);
            f32x4 a = {0.f,0.f,0.f,0.f};
            a = __builtin_amdgcn_mfma_f32_16x16x32_bf16(qf0.v, kf0.v, a, 0, 0, 0);
            a = __builtin_amdgcn_mfma_f32_16x16x32_bf16(qf1.v, kf1.v, a, 0, 0, 0);
            sc[ct] = a;
        }

        unsigned long long mb[4];
        #pragma unroll
        for (int r = 0; r < 4; ++r) mb[r] = Mb[quad * 4 + r][kw];

        #pragma unroll
        for (int ct = 0; ct < 4; ++ct) {
            #pragma unroll
            for (int r = 0; r < 4; ++r) {
                float p = ((mb[r] >> (ct * 16 + lm)) & 1ull)
                          ? __expf(sc[ct][r] * 0.125f) : 0.f;
                sc[ct][r] = p;
                lsum[r] += p;
            }
        }

        // ---- P: C-layout -> A-layout via own LDS slice (no barrier) ----
        #pragma unroll
        for (int ct = 0; ct < 4; ++ct)
            #pragma unroll
            for (int r = 0; r < 4; ++r)
                Plds[w][(quad * 4 + r) * 72 + ct * 16 + lm] = f2bf(sc[ct][r]);

        // ---- PV: vf loads lane-contiguous (frag layout) ----
        #pragma unroll
        for (int ks = 0; ks < 2; ++ks) {
            FragU pf;
            pf.u = *(const u32x4*)&Plds[w][lm * 72 + ks * 32 + quad * 8];
            const int sb = (k0 >> 5) + ks;
            #pragma unroll
            for (int dt = 0; dt < 4; ++dt) {
                FragU vf;
                vf.u = vbase[(sb * 4 + dt) * 64 + lane];
                o[dt] = __builtin_amdgcn_mfma_f32_16x16x32_bf16(pf.v, vf.v, o[dt], 0, 0, 0);
            }
        }
    }

    // ---- l reduce over 16-lane row groups ----
    #pragma unroll
    for (int r = 0; r < 4; ++r)
        #pragma unroll
        for (int off = 1; off <= 8; off <<= 1)
            lsum[r] += __shfl_xor(lsum[r], off, 64);

    #pragma unroll
    for (int dt = 0; dt < 4; ++dt)
        #pragma unroll
        for (int r = 0; r < 4; ++r)
            Olds[w][(quad * 4 + r) * 64 + dt * 16 + lm] = o[dt][r];
    if (lm == 0)
        #pragma unroll
        for (int r = 0; r < 4; ++r) llds[w][quad * 4 + r] = lsum[r];
    __syncthreads();

    // ---- merge 8 wave-partials, normalize, store ----
    #pragma unroll
    for (int i = 0; i < 2; ++i) {
        int e = i * 512 + tid;
        int q = e >> 6, d = e & 63;
        float L = 0.f, val = 0.f;
        #pragma unroll
        for (int ww = 0; ww < 8; ++ww) {
            L   += llds[ww][q];
            val += Olds[ww][q * 64 + d];
        }
        out[(b * 2048 + q0 + q) * 64 + d] = val / L;
    }
}

extern "C" void kernel_launch(void* const* d_in, const int* in_sizes, int n_in,
                              void* d_out, int out_size, void* d_ws, size_t ws_size,
                              hipStream_t stream) {
    const float* Q   = (const float*)d_in[0];
    const float* K   = (const float*)d_in[1];
    const float* V   = (const float*)d_in[2];
    const int* mask  = (const int*)d_in[3];
    const float* Wq  = (const float*)d_in[4];
    const float* bq  = (const float*)d_in[5];
    const float* Wk  = (const float*)d_in[6];
    const float* bk  = (const float*)d_in[7];
    const float* Wv  = (const float*)d_in[8];
    const float* bv  = (const float*)d_in[9];
    float* out = (float*)d_out;

    char* ws = (char*)d_ws;
    unsigned short* Qb = (unsigned short*)(ws);                          // 1 MB
    unsigned short* Kb = (unsigned short*)(ws + (1u << 20));             // 1 MB
    unsigned short* Vf = (unsigned short*)(ws + (2u << 20));             // 1 MB
    u32x4* Wt4 = (u32x4*)(ws + (3u << 20));                              // 384 KB
    unsigned long long* bits = (unsigned long long*)(ws + (4u << 20));   // 2 MB

    hipLaunchKernelGGL(cvt_w_kernel, dim3(96), dim3(256), 0, stream, Wq, Wk, Wv, Wt4);
    hipLaunchKernelGGL(proj_mask_kernel, dim3(3584), dim3(256), 0, stream,
                       Q, K, V, Wt4, bq, bk, bv, mask, Qb, Kb, Vf, bits);
    hipLaunchKernelGGL(attn_kernel, dim3(128, 4), dim3(512), 0, stream,
                       Qb, Kb, (const u32x4*)Vf, bits, out);
}